// Round 1
// baseline (451.117 us; speedup 1.0000x reference)
//
#include <hip/hip_runtime.h>
#include <stdint.h>

typedef __bf16 bf16x8 __attribute__((ext_vector_type(8)));
typedef float  f32x4  __attribute__((ext_vector_type(4)));

#define MTOT 16384
#define NCH 32         // chunks per batch -> 32*32 = 1024 blocks
#define CHUNK_M 512    // m-columns per gram block
#define SUB_M 256      // staged sub-tile
#define TSTR 264       // LDS tile stride in bf16 elems (256+8: 16B aligned)

__device__ __forceinline__ unsigned short f2bf(float v) {
  unsigned int u = __float_as_uint(v);
  u += 0x7fffu + ((u >> 16) & 1u);   // RNE
  return (unsigned short)(u >> 16);
}

// ---------------- Kernel 1: fused (x - prev) -> bf16 -> per-chunk Gram partial + row-sum partial
// Row sums accumulate in REGISTERS (rs[16], statically indexed) -- no LDS atomics.
__global__ __launch_bounds__(256) void gram_k(const float* __restrict__ x,
                                              const float* __restrict__ prev,
                                              float* __restrict__ Gpart,
                                              float* __restrict__ MuPart) {
  __shared__ unsigned short tile[64 * TSTR];
  const int tid  = threadIdx.x;
  const int wv   = tid >> 6;
  const int lane = tid & 63;
  const int b    = blockIdx.x >> 5;
  const int ch   = blockIdx.x & 31;
  const size_t base = (size_t)b * 64 * MTOT + (size_t)ch * CHUNK_M;

  f32x4 acc[4];
#pragma unroll
  for (int t = 0; t < 4; ++t) acc[t] = (f32x4){0.f, 0.f, 0.f, 0.f};
  float rs[16];
#pragma unroll
  for (int i = 0; i < 16; ++i) rs[i] = 0.f;

  for (int sub = 0; sub < 2; ++sub) {
    const int m0 = sub * SUB_M;
    // stage 64 rows x 256 m as bf16 (coalesced float4 loads; one wave per row per step)
#pragma unroll
    for (int it = 0; it < 16; ++it) {
      const int row = it * 4 + wv;            // wave-uniform row
      const float4 a = *((const float4*)(x    + base + (size_t)row * MTOT + m0) + lane);
      const float4 p = *((const float4*)(prev + base + (size_t)row * MTOT + m0) + lane);
      float dx = a.x - p.x, dy = a.y - p.y, dz = a.z - p.z, dw = a.w - p.w;
      rs[it] += (dx + dy) + (dz + dw);        // register accumulation, no atomics
      ushort4 q;
      q.x = f2bf(dx); q.y = f2bf(dy); q.z = f2bf(dz); q.w = f2bf(dw);
      *(ushort4*)&tile[row * TSTR + lane * 4] = q;
    }
    __syncthreads();
    // syrk: wave w owns row-strip w; frag s doubles as A (strip w) and B (strip t)
#pragma unroll
    for (int ks = 0; ks < 8; ++ks) {
      const int mloc = ks * 32 + (lane >> 4) * 8;
      const int r    = lane & 15;
      bf16x8 fr[4];
#pragma unroll
      for (int s = 0; s < 4; ++s)
        fr[s] = *(const bf16x8*)&tile[(s * 16 + r) * TSTR + mloc];
#pragma unroll
      for (int t = 0; t < 4; ++t)
        acc[t] = __builtin_amdgcn_mfma_f32_16x16x32_bf16(fr[wv], fr[t], acc[t], 0, 0, 0);
    }
    __syncthreads();
  }

  float* gp = Gpart + (size_t)blockIdx.x * 4096;
  const int r4 = (lane >> 4) * 4;
  const int c  = lane & 15;
#pragma unroll
  for (int t = 0; t < 4; ++t)
#pragma unroll
    for (int rr = 0; rr < 4; ++rr)
      gp[(wv * 16 + r4 + rr) * 64 + t * 16 + c] = acc[t][rr];

  // cross-lane reduce of per-row partial sums; wave wv owns rows it*4+wv
#pragma unroll
  for (int it = 0; it < 16; ++it) {
    float v = rs[it];
#pragma unroll
    for (int off = 32; off; off >>= 1) v += __shfl_xor(v, off);
    if (lane == 0) MuPart[(size_t)blockIdx.x * 64 + it * 4 + wv] = v;
  }
}

// ---------------- 64x64 f32 matmul in LDS (stride 68)
// 256-thread variant: 4x4 register tile per thread
__device__ __forceinline__ void mm64h(float* __restrict__ D, const float* __restrict__ A,
                                      const float* __restrict__ B, int t, bool nsform) {
  const int i0 = (t >> 4) * 4;
  const int j0 = (t & 15) * 4;
  float accv[4][4] = {};
  for (int kq = 0; kq < 16; ++kq) {
    float4 av[4], bv[4];
#pragma unroll
    for (int r = 0; r < 4; ++r) av[r] = *(const float4*)&A[(i0 + r) * 68 + kq * 4];
#pragma unroll
    for (int r = 0; r < 4; ++r) bv[r] = *(const float4*)&B[(kq * 4 + r) * 68 + j0];
#pragma unroll
    for (int r = 0; r < 4; ++r) {
      const float ar[4] = {av[r].x, av[r].y, av[r].z, av[r].w};
#pragma unroll
      for (int q = 0; q < 4; ++q) {
        const float bq[4] = {bv[q].x, bv[q].y, bv[q].z, bv[q].w};
#pragma unroll
        for (int cc = 0; cc < 4; ++cc)
          accv[r][cc] = fmaf(ar[q], bq[cc], accv[r][cc]);
      }
    }
  }
#pragma unroll
  for (int r = 0; r < 4; ++r)
#pragma unroll
    for (int cc = 0; cc < 4; ++cc) {
      float v = accv[r][cc];
      if (nsform) v = ((i0 + r) == (j0 + cc) ? 1.5f : 0.f) - 0.5f * v;  // 0.5*(3I - P)
      D[(i0 + r) * 68 + j0 + cc] = v;
    }
}

// 512-thread variant: 2x4 register tile per thread
__device__ __forceinline__ void mm64f(float* __restrict__ D, const float* __restrict__ A,
                                      const float* __restrict__ B, int t, bool nsform) {
  const int i0 = (t >> 4) * 2;
  const int j0 = (t & 15) * 4;
  float accv[2][4] = {};
  for (int kq = 0; kq < 16; ++kq) {
    float4 av[2], bv[4];
#pragma unroll
    for (int r = 0; r < 2; ++r) av[r] = *(const float4*)&A[(i0 + r) * 68 + kq * 4];
#pragma unroll
    for (int r = 0; r < 4; ++r) bv[r] = *(const float4*)&B[(kq * 4 + r) * 68 + j0];
#pragma unroll
    for (int r = 0; r < 2; ++r) {
      const float ar[4] = {av[r].x, av[r].y, av[r].z, av[r].w};
#pragma unroll
      for (int q = 0; q < 4; ++q) {
        const float bq[4] = {bv[q].x, bv[q].y, bv[q].z, bv[q].w};
#pragma unroll
        for (int cc = 0; cc < 4; ++cc)
          accv[r][cc] = fmaf(ar[q], bq[cc], accv[r][cc]);
      }
    }
  }
#pragma unroll
  for (int r = 0; r < 2; ++r)
#pragma unroll
    for (int cc = 0; cc < 4; ++cc) {
      float v = accv[r][cc];
      if (nsform) v = ((i0 + r) == (j0 + cc) ? 1.5f : 0.f) - 0.5f * v;
      D[(i0 + r) * 68 + j0 + cc] = v;
    }
}

// ---------------- Kernel 2: per-batch cov assembly + Newton-Schulz + MLP gate
// 512 threads: ZY matmuls split over all 8 waves; Y'=Y@ZY and Z'=ZY@Z run concurrently on half-blocks.
__global__ __launch_bounds__(512) void ns_k(const float* __restrict__ Gpart,
                                            const float* __restrict__ MuPart,
                                            const float* __restrict__ w1, const float* __restrict__ b1,
                                            const float* __restrict__ w2, const float* __restrict__ b2,
                                            float* __restrict__ yout) {
  __shared__ float bufs[6][64 * 68];   // ~104.4 KB
  __shared__ float smu[64], sS[64], sh[8], snorm;
  const int b = blockIdx.x, tid = threadIdx.x;

  if (tid < 64) {
    float m = 0.f;
    for (int p = 0; p < NCH; ++p) m += MuPart[(size_t)(b * NCH + p) * 64 + tid];
    smu[tid] = m * (1.f / 16384.f);
  }
  __syncthreads();
  // cov = G/M - mu mu^T  -> bufs[0]
  for (int e = tid; e < 4096; e += 512) {
    int i = e >> 6, j = e & 63;
    float g = 0.f;
    for (int p = 0; p < NCH; ++p) g += Gpart[(size_t)(b * NCH + p) * 4096 + e];
    bufs[0][i * 68 + j] = g * (1.f / 16384.f) - smu[i] * smu[j];
  }
  __syncthreads();
  if (tid < 64) {
    float v = bufs[0][tid * 68 + tid];
    for (int off = 32; off; off >>= 1) v += __shfl_down(v, off);
    if (tid == 0) snorm = v;
  }
  __syncthreads();
  const float normA = snorm;
  const float inv = 1.f / normA;
  // An (in place) and ZY0 = 0.5*(3I - An)
  for (int e = tid; e < 4096; e += 512) {
    int i = e >> 6, j = e & 63;
    float an = bufs[0][i * 68 + j] * inv;
    bufs[0][i * 68 + j] = an;
    bufs[1][i * 68 + j] = 0.5f * ((i == j ? 3.f : 0.f) - an);
  }
  __syncthreads();
  mm64f(bufs[2], bufs[0], bufs[1], tid, false);   // Y = An @ ZY0  (all 512)
  __syncthreads();
  float *Y = bufs[2], *Z = bufs[1], *Yn = bufs[4], *Zn = bufs[5];
  for (int it = 0; it < 3; ++it) {
    mm64f(bufs[3], Z, Y, tid, true);              // ZY = 0.5*(3I - Z@Y)  (all 512)
    __syncthreads();
    if (tid < 256) mm64h(Yn, Y, bufs[3], tid, false);        // Y' = Y @ ZY   (waves 0-3)
    else           mm64h(Zn, bufs[3], Z, tid - 256, false);  // Z' = ZY @ Z   (waves 4-7)
    __syncthreads();
    float* t0 = Y; Y = Yn; Yn = t0;
    float* t1 = Z; Z = Zn; Zn = t1;
  }
  mm64f(bufs[3], Z, Y, tid, true);
  __syncthreads();
  mm64f(Yn, Y, bufs[3], tid, false);              // YZY (all 512)
  __syncthreads();
  if (tid < 64) {
    float s = 0.f;
    for (int i = 0; i < 64; ++i) s += Yn[i * 68 + tid];
    sS[tid] = s * (1.f / 64.f) * sqrtf(normA);   // column mean (axis=1) * sqrt(trace)
  }
  __syncthreads();
  if (tid < 8) {
    float h = b1[tid];
    for (int c2 = 0; c2 < 64; ++c2) h += w1[tid * 64 + c2] * sS[c2];
    sh[tid] = fmaxf(h, 0.f);
  }
  __syncthreads();
  if (tid < 64) {
    float l = b2[tid];
    for (int o = 0; o < 8; ++o) l += w2[tid * 8 + o] * sh[o];
    yout[b * 64 + tid] = 1.f / (1.f + expf(-l));
  }
}

// ---------------- Kernel 3: out = y[b,c] * (x - prev)
__global__ __launch_bounds__(256) void scale_k(const float* __restrict__ x,
                                               const float* __restrict__ prev,
                                               const float* __restrict__ y,
                                               float* __restrict__ out) {
  size_t f = (size_t)blockIdx.x * 256 + threadIdx.x;   // float4 index, total 8388608
  size_t e = f * 4;
  int bc = (int)(e >> 14);                              // (b*64 + c)
  float s = y[bc];
  float4 a = ((const float4*)x)[f];
  float4 p = ((const float4*)prev)[f];
  float4 o;
  o.x = (a.x - p.x) * s; o.y = (a.y - p.y) * s;
  o.z = (a.z - p.z) * s; o.w = (a.w - p.w) * s;
  ((float4*)out)[f] = o;
}

extern "C" void kernel_launch(void* const* d_in, const int* in_sizes, int n_in,
                              void* d_out, int out_size, void* d_ws, size_t ws_size,
                              hipStream_t stream) {
  (void)in_sizes; (void)n_in; (void)out_size; (void)ws_size;
  const float* prev = (const float*)d_in[0];
  const float* x    = (const float*)d_in[1];
  const float* w1   = (const float*)d_in[2];
  const float* b1   = (const float*)d_in[3];
  const float* w2   = (const float*)d_in[4];
  const float* b2   = (const float*)d_in[5];
  float* out = (float*)d_out;

  float* Gpart  = (float*)d_ws;                      // 1024*4096 f32 = 16 MB
  float* MuPart = Gpart + (size_t)1024 * 4096;       // 1024*64 f32
  float* yv     = MuPart + (size_t)1024 * 64;        // 32*64 f32

  gram_k<<<1024, 256, 0, stream>>>(x, prev, Gpart, MuPart);
  ns_k<<<32, 512, 0, stream>>>(Gpart, MuPart, w1, b1, w2, b2, yv);
  scale_k<<<32768, 256, 0, stream>>>(x, prev, yv, out);
}

// Round 2
// 440.172 us; speedup vs baseline: 1.0249x; 1.0249x over previous
//
#include <hip/hip_runtime.h>
#include <stdint.h>

typedef __bf16 bf16x8 __attribute__((ext_vector_type(8)));
typedef __bf16 bf16x4 __attribute__((ext_vector_type(4)));
typedef float  f32x4  __attribute__((ext_vector_type(4)));
typedef unsigned int u32;

#define MTOT 16384
#define NCH 16         // chunks per batch -> 32*16 = 512 blocks
#define CHUNK_M 1024   // m-columns per gram block
#define NSUB 16        // 64 m per sub-tile
#define TSTR 72        // bf16 tile stride (64+8, 16B-aligned rows)

#define GLOAD_LDS(g, l) \
  __builtin_amdgcn_global_load_lds((const __attribute__((address_space(1))) u32*)(g), \
                                   (__attribute__((address_space(3))) u32*)(l), 16, 0, 0)

__device__ __forceinline__ void fence_barrier() {
  asm volatile("" ::: "memory");
  __builtin_amdgcn_s_barrier();
  asm volatile("" ::: "memory");
}

// ---------------- Kernel 1: async-staged (x - prev) Gram + row-sum partials
// f32 x/prev sub-tiles stream into LDS via global_load_lds (counted vmcnt, raw barriers);
// cvt pass does diff -> hw bf16 cast -> tile; MFMA syrk consumes tile. K-order = ascending
// (bit-identical Gram vs previous version).
__global__ __launch_bounds__(256) void gram_k(const float* __restrict__ x,
                                              const float* __restrict__ prev,
                                              float* __restrict__ Gpart,
                                              float* __restrict__ MuPart) {
  __shared__ float  fbuf[2][2][64 * 64];   // [dbuf][x|prev][64 rows x 64 m] f32 = 64 KB
  __shared__ __bf16 tile[64 * TSTR];       // 9 KB
  const int tid  = threadIdx.x;
  const int wv   = tid >> 6;
  const int lane = tid & 63;
  const int b    = blockIdx.x >> 4;
  const int ch   = blockIdx.x & 15;
  const size_t base = (size_t)b * 64 * MTOT + (size_t)ch * CHUNK_M;

  f32x4 acc[4];
#pragma unroll
  for (int t = 0; t < 4; ++t) acc[t] = (f32x4){0.f, 0.f, 0.f, 0.f};
  float rs[4] = {0.f, 0.f, 0.f, 0.f};

  // issue one sub-tile's 32 async loads (8 per wave): instr idx -> {array, KB index}
  auto issue = [&](int sub, int cb) {
#pragma unroll
    for (int t = 0; t < 8; ++t) {
      const int idx = wv * 8 + t;          // 0..31
      const int arr = idx >> 4;            // 0: x, 1: prev
      const int i   = idx & 15;            // which KB of the 16 KB buffer
      const float* g = (arr ? prev : x) + base + (size_t)(4 * i + (lane >> 4)) * MTOT
                       + sub * 64 + (lane & 15) * 4;
      float* l = &fbuf[cb][arr][i * 256];  // wave-uniform dest; lanes land at +lane*16B
      GLOAD_LDS(g, l);
    }
  };

  auto cvt_syrk = [&](int cb) {
    // cvt: linear float4 mapping -> conflict-free ds_read_b128; row = f4>>4, col4 = f4&15
    const float4* fx = (const float4*)fbuf[cb][0];
    const float4* fp = (const float4*)fbuf[cb][1];
#pragma unroll
    for (int j = 0; j < 4; ++j) {
      const int f4 = tid + j * 256;
      const float4 a = fx[f4];
      const float4 p = fp[f4];
      float dx = a.x - p.x, dy = a.y - p.y, dz = a.z - p.z, dw = a.w - p.w;
      rs[j] += (dx + dy) + (dz + dw);
      bf16x4 q = {(__bf16)dx, (__bf16)dy, (__bf16)dz, (__bf16)dw};
      *(bf16x4*)&tile[(f4 >> 4) * TSTR + (f4 & 15) * 4] = q;
    }
    asm volatile("s_waitcnt lgkmcnt(0)" ::: "memory");
    fence_barrier();
    // syrk on the 64x64 bf16 tile (K=64 -> 2 ks steps)
#pragma unroll
    for (int ks = 0; ks < 2; ++ks) {
      const int mloc = ks * 32 + (lane >> 4) * 8;
      const int r    = lane & 15;
      bf16x8 fr[4];
#pragma unroll
      for (int s = 0; s < 4; ++s)
        fr[s] = *(const bf16x8*)&tile[(s * 16 + r) * TSTR + mloc];
#pragma unroll
      for (int t = 0; t < 4; ++t)
        acc[t] = __builtin_amdgcn_mfma_f32_16x16x32_bf16(fr[wv], fr[t], acc[t], 0, 0, 0);
    }
    asm volatile("s_waitcnt lgkmcnt(0)" ::: "memory");  // reads done before tile overwrite
    fence_barrier();
  };

  issue(0, 0);
  for (int s = 0; s < NSUB - 1; ++s) {
    issue(s + 1, (s & 1) ^ 1);
    asm volatile("s_waitcnt vmcnt(8)" ::: "memory");   // sub s's 8 done; s+1's in flight
    fence_barrier();
    cvt_syrk(s & 1);
  }
  asm volatile("s_waitcnt vmcnt(0)" ::: "memory");
  fence_barrier();
  cvt_syrk((NSUB - 1) & 1);

  float* gp = Gpart + (size_t)blockIdx.x * 4096;
  const int r4 = (lane >> 4) * 4;
  const int c  = lane & 15;
#pragma unroll
  for (int t = 0; t < 4; ++t)
#pragma unroll
    for (int rr = 0; rr < 4; ++rr)
      gp[(wv * 16 + r4 + rr) * 64 + t * 16 + c] = acc[t][rr];

  // row-sum: 16 consecutive lanes share row R = (tid>>4) + 16*j
#pragma unroll
  for (int j = 0; j < 4; ++j) {
    float v = rs[j];
    v += __shfl_xor(v, 1); v += __shfl_xor(v, 2);
    v += __shfl_xor(v, 4); v += __shfl_xor(v, 8);
    if ((tid & 15) == 0) MuPart[(size_t)blockIdx.x * 64 + (tid >> 4) + 16 * j] = v;
  }
}

// ---------------- 64x64 f32 matmul in LDS (stride 68), 4x4 tile, 256 threads
__device__ __forceinline__ void mm64h(float* __restrict__ D, const float* __restrict__ A,
                                      const float* __restrict__ B, int t, bool nsform) {
  const int i0 = (t >> 4) * 4;
  const int j0 = (t & 15) * 4;
  float accv[4][4] = {};
  for (int kq = 0; kq < 16; ++kq) {
    float4 av[4], bv[4];
#pragma unroll
    for (int r = 0; r < 4; ++r) av[r] = *(const float4*)&A[(i0 + r) * 68 + kq * 4];
#pragma unroll
    for (int r = 0; r < 4; ++r) bv[r] = *(const float4*)&B[(kq * 4 + r) * 68 + j0];
#pragma unroll
    for (int r = 0; r < 4; ++r) {
      const float ar[4] = {av[r].x, av[r].y, av[r].z, av[r].w};
#pragma unroll
      for (int q = 0; q < 4; ++q) {
        const float bq[4] = {bv[q].x, bv[q].y, bv[q].z, bv[q].w};
#pragma unroll
        for (int cc = 0; cc < 4; ++cc)
          accv[r][cc] = fmaf(ar[q], bq[cc], accv[r][cc]);
      }
    }
  }
#pragma unroll
  for (int r = 0; r < 4; ++r)
#pragma unroll
    for (int cc = 0; cc < 4; ++cc) {
      float v = accv[r][cc];
      if (nsform) v = ((i0 + r) == (j0 + cc) ? 1.5f : 0.f) - 0.5f * v;  // 0.5*(3I - P)
      D[(i0 + r) * 68 + j0 + cc] = v;
    }
}

// ---------------- Kernel 2: per-batch cov assembly + Newton-Schulz + MLP gate
// All matmuls use the 4x4-tile mm64h (best LDS-reads/FMA ratio); 512 threads exist to run
// the independent Y'=Y@ZY / Z'=ZY@Z pair concurrently on half-blocks.
__global__ __launch_bounds__(512) void ns_k(const float* __restrict__ Gpart,
                                            const float* __restrict__ MuPart,
                                            const float* __restrict__ w1, const float* __restrict__ b1,
                                            const float* __restrict__ w2, const float* __restrict__ b2,
                                            float* __restrict__ yout) {
  __shared__ float bufs[6][64 * 68];   // ~104.4 KB
  __shared__ float smu[64], sS[64], sh[8], snorm;
  const int b = blockIdx.x, tid = threadIdx.x;

  if (tid < 64) {
    float m = 0.f;
    for (int p = 0; p < NCH; ++p) m += MuPart[(size_t)(b * NCH + p) * 64 + tid];
    smu[tid] = m * (1.f / 16384.f);
  }
  __syncthreads();
  for (int e = tid; e < 4096; e += 512) {
    int i = e >> 6, j = e & 63;
    float g = 0.f;
    for (int p = 0; p < NCH; ++p) g += Gpart[(size_t)(b * NCH + p) * 4096 + e];
    bufs[0][i * 68 + j] = g * (1.f / 16384.f) - smu[i] * smu[j];
  }
  __syncthreads();
  if (tid < 64) {
    float v = bufs[0][tid * 68 + tid];
    for (int off = 32; off; off >>= 1) v += __shfl_down(v, off);
    if (tid == 0) snorm = v;
  }
  __syncthreads();
  const float normA = snorm;
  const float inv = 1.f / normA;
  for (int e = tid; e < 4096; e += 512) {
    int i = e >> 6, j = e & 63;
    float an = bufs[0][i * 68 + j] * inv;
    bufs[0][i * 68 + j] = an;
    bufs[1][i * 68 + j] = 0.5f * ((i == j ? 3.f : 0.f) - an);
  }
  __syncthreads();
  if (tid < 256) mm64h(bufs[2], bufs[0], bufs[1], tid, false);   // Y = An @ ZY0
  __syncthreads();
  float *Y = bufs[2], *Z = bufs[1], *Yn = bufs[4], *Zn = bufs[5];
  for (int it = 0; it < 3; ++it) {
    if (tid < 256) mm64h(bufs[3], Z, Y, tid, true);              // ZY = 0.5*(3I - Z@Y)
    __syncthreads();
    if (tid < 256) mm64h(Yn, Y, bufs[3], tid, false);            // Y' = Y @ ZY
    else           mm64h(Zn, bufs[3], Z, tid - 256, false);      // Z' = ZY @ Z
    __syncthreads();
    float* t0 = Y; Y = Yn; Yn = t0;
    float* t1 = Z; Z = Zn; Zn = t1;
  }
  if (tid < 256) mm64h(bufs[3], Z, Y, tid, true);
  __syncthreads();
  if (tid < 256) mm64h(Yn, Y, bufs[3], tid, false);              // YZY
  __syncthreads();
  if (tid < 64) {
    float s = 0.f;
    for (int i = 0; i < 64; ++i) s += Yn[i * 68 + tid];
    sS[tid] = s * (1.f / 64.f) * sqrtf(normA);
  }
  __syncthreads();
  if (tid < 8) {
    float h = b1[tid];
    for (int c2 = 0; c2 < 64; ++c2) h += w1[tid * 64 + c2] * sS[c2];
    sh[tid] = fmaxf(h, 0.f);
  }
  __syncthreads();
  if (tid < 64) {
    float l = b2[tid];
    for (int o = 0; o < 8; ++o) l += w2[tid * 8 + o] * sh[o];
    yout[b * 64 + tid] = 1.f / (1.f + expf(-l));
  }
}

// ---------------- Kernel 3: out = y[b,c] * (x - prev), capped grid-stride
__global__ __launch_bounds__(256) void scale_k(const float* __restrict__ x,
                                               const float* __restrict__ prev,
                                               const float* __restrict__ y,
                                               float* __restrict__ out) {
  const size_t stride = (size_t)gridDim.x * 256;
  for (size_t f = (size_t)blockIdx.x * 256 + threadIdx.x; f < 8388608; f += stride) {
    size_t e = f * 4;
    int bc = (int)(e >> 14);
    float s = y[bc];
    float4 a = ((const float4*)x)[f];
    float4 p = ((const float4*)prev)[f];
    float4 o;
    o.x = (a.x - p.x) * s; o.y = (a.y - p.y) * s;
    o.z = (a.z - p.z) * s; o.w = (a.w - p.w) * s;
    ((float4*)out)[f] = o;
  }
}

extern "C" void kernel_launch(void* const* d_in, const int* in_sizes, int n_in,
                              void* d_out, int out_size, void* d_ws, size_t ws_size,
                              hipStream_t stream) {
  (void)in_sizes; (void)n_in; (void)out_size; (void)ws_size;
  const float* prev = (const float*)d_in[0];
  const float* x    = (const float*)d_in[1];
  const float* w1   = (const float*)d_in[2];
  const float* b1   = (const float*)d_in[3];
  const float* w2   = (const float*)d_in[4];
  const float* b2   = (const float*)d_in[5];
  float* out = (float*)d_out;

  float* Gpart  = (float*)d_ws;                     // 512*4096 f32 = 8 MB
  float* MuPart = Gpart + (size_t)512 * 4096;       // 512*64 f32
  float* yv     = MuPart + (size_t)512 * 64;        // 32*64 f32

  gram_k<<<512, 256, 0, stream>>>(x, prev, Gpart, MuPart);
  ns_k<<<32, 512, 0, stream>>>(Gpart, MuPart, w1, b1, w2, b2, yv);
  scale_k<<<2048, 256, 0, stream>>>(x, prev, yv, out);
}

// Round 3
// 408.311 us; speedup vs baseline: 1.1048x; 1.0780x over previous
//
#include <hip/hip_runtime.h>
#include <stdint.h>

typedef __bf16 bf16x8 __attribute__((ext_vector_type(8)));
typedef __bf16 bf16x4 __attribute__((ext_vector_type(4)));
typedef float  f32x4  __attribute__((ext_vector_type(4)));

#define MTOT 16384
#define NCH 32         // chunks per batch -> 32*32 = 1024 blocks
#define CHUNK_M 512    // m-columns per gram block
#define SS 256         // superstep cols (tile width)
#define TSTR 264       // bf16 tile stride (256+8)

// ---------------- Kernel 1: register-staged (x - prev) Gram + row-sum partials
// Each wave owns 8 full rows; loads are float4/lane = 1 KB CONTIGUOUS per instruction
// (16 in flight per wave). diff + bf16 cvt in regs -> direct bf16 tile write. No f32 LDS.
__global__ __launch_bounds__(512, 4) void gram_k(const float* __restrict__ x,
                                                 const float* __restrict__ prev,
                                                 float* __restrict__ Gpart,
                                                 float* __restrict__ MuPart) {
  __shared__ __bf16 tile[64 * TSTR];   // 33792 B
  const int tid  = threadIdx.x;
  const int wv   = tid >> 6;           // 0..7
  const int lane = tid & 63;
  const int b    = blockIdx.x >> 5;
  const int ch   = blockIdx.x & 31;
  const size_t base = (size_t)b * 64 * MTOT + (size_t)ch * CHUNK_M;
  const int arow = wv >> 1;            // MFMA row-strip 0..3
  const int bc0  = (wv & 1) * 2;       // MFMA col-strips bc0, bc0+1

  f32x4 acc[2];
  acc[0] = (f32x4){0.f,0.f,0.f,0.f};
  acc[1] = (f32x4){0.f,0.f,0.f,0.f};
  float rs[8] = {0.f,0.f,0.f,0.f,0.f,0.f,0.f,0.f};

  const float* xb = x    + base + (size_t)(wv * 8) * MTOT + lane * 4;
  const float* pb = prev + base + (size_t)(wv * 8) * MTOT + lane * 4;

#pragma unroll
  for (int ss = 0; ss < 2; ++ss) {
    float4 xr[8], pr[8];
#pragma unroll
    for (int i = 0; i < 8; ++i) {
      xr[i] = *(const float4*)(xb + (size_t)i * MTOT + ss * SS);
      pr[i] = *(const float4*)(pb + (size_t)i * MTOT + ss * SS);
    }
#pragma unroll
    for (int i = 0; i < 8; ++i) {
      float dx = xr[i].x - pr[i].x, dy = xr[i].y - pr[i].y;
      float dz = xr[i].z - pr[i].z, dw = xr[i].w - pr[i].w;
      rs[i] += (dx + dy) + (dz + dw);
      bf16x4 q = {(__bf16)dx, (__bf16)dy, (__bf16)dz, (__bf16)dw};
      *(bf16x4*)&tile[(wv * 8 + i) * TSTR + lane * 4] = q;
    }
    __syncthreads();
    // syrk over the 64x256 tile: 8 K-slices of 32
#pragma unroll
    for (int ks = 0; ks < 8; ++ks) {
      const int mloc = ks * 32 + (lane >> 4) * 8;
      const int r    = lane & 15;
      bf16x8 fa  = *(const bf16x8*)&tile[(arow * 16 + r) * TSTR + mloc];
      bf16x8 fb0 = *(const bf16x8*)&tile[(bc0 * 16 + r) * TSTR + mloc];
      bf16x8 fb1 = *(const bf16x8*)&tile[((bc0 + 1) * 16 + r) * TSTR + mloc];
      acc[0] = __builtin_amdgcn_mfma_f32_16x16x32_bf16(fa, fb0, acc[0], 0, 0, 0);
      acc[1] = __builtin_amdgcn_mfma_f32_16x16x32_bf16(fa, fb1, acc[1], 0, 0, 0);
    }
    __syncthreads();
  }

  float* gp = Gpart + (size_t)blockIdx.x * 4096;
  const int r4 = (lane >> 4) * 4;
  const int c  = lane & 15;
#pragma unroll
  for (int t = 0; t < 2; ++t)
#pragma unroll
    for (int rr = 0; rr < 4; ++rr)
      gp[(arow * 16 + r4 + rr) * 64 + (bc0 + t) * 16 + c] = acc[t][rr];

  // per-row sums: wave wv owns rows wv*8+i; all 64 lanes hold distinct cols
#pragma unroll
  for (int i = 0; i < 8; ++i) {
    float v = rs[i];
    v += __shfl_xor(v, 1);  v += __shfl_xor(v, 2);  v += __shfl_xor(v, 4);
    v += __shfl_xor(v, 8);  v += __shfl_xor(v, 16); v += __shfl_xor(v, 32);
    if (lane == 0) MuPart[(size_t)blockIdx.x * 64 + wv * 8 + i] = v;
  }
}

// ---------------- 64x64 f32 matmul in LDS (stride 68), 4x4 tile, 256 threads
__device__ __forceinline__ void mm64(float* __restrict__ D, const float* __restrict__ A,
                                     const float* __restrict__ B, int t, bool nsform) {
  const int i0 = (t >> 4) * 4;
  const int j0 = (t & 15) * 4;
  float accv[4][4] = {};
  for (int kq = 0; kq < 16; ++kq) {
    float4 av[4], bv[4];
#pragma unroll
    for (int r = 0; r < 4; ++r) av[r] = *(const float4*)&A[(i0 + r) * 68 + kq * 4];
#pragma unroll
    for (int r = 0; r < 4; ++r) bv[r] = *(const float4*)&B[(kq * 4 + r) * 68 + j0];
#pragma unroll
    for (int r = 0; r < 4; ++r) {
      const float ar[4] = {av[r].x, av[r].y, av[r].z, av[r].w};
#pragma unroll
      for (int q = 0; q < 4; ++q) {
        const float bq[4] = {bv[q].x, bv[q].y, bv[q].z, bv[q].w};
#pragma unroll
        for (int cc = 0; cc < 4; ++cc)
          accv[r][cc] = fmaf(ar[q], bq[cc], accv[r][cc]);
      }
    }
  }
#pragma unroll
  for (int r = 0; r < 4; ++r)
#pragma unroll
    for (int cc = 0; cc < 4; ++cc) {
      float v = accv[r][cc];
      if (nsform) v = ((i0 + r) == (j0 + cc) ? 1.5f : 0.f) - 0.5f * v;  // 0.5*(3I - P)
      D[(i0 + r) * 68 + j0 + cc] = v;
    }
}

// ---------------- Kernel 2: per-batch cov assembly + Newton-Schulz + MLP gate (R0 structure)
__global__ __launch_bounds__(256) void ns_k(const float* __restrict__ Gpart,
                                            const float* __restrict__ MuPart,
                                            const float* __restrict__ w1, const float* __restrict__ b1,
                                            const float* __restrict__ w2, const float* __restrict__ b2,
                                            float* __restrict__ yout) {
  __shared__ float bufs[6][64 * 68];   // ~104.4 KB
  __shared__ float smu[64], sS[64], sh[8], snorm;
  const int b = blockIdx.x, tid = threadIdx.x;

  if (tid < 64) {
    float m = 0.f;
    for (int p = 0; p < NCH; ++p) m += MuPart[(size_t)(b * NCH + p) * 64 + tid];
    smu[tid] = m * (1.f / 16384.f);
  }
  __syncthreads();
  for (int e = tid; e < 4096; e += 256) {
    int i = e >> 6, j = e & 63;
    float g = 0.f;
    for (int p = 0; p < NCH; ++p) g += Gpart[(size_t)(b * NCH + p) * 4096 + e];
    bufs[0][i * 68 + j] = g * (1.f / 16384.f) - smu[i] * smu[j];
  }
  __syncthreads();
  if (tid < 64) {
    float v = bufs[0][tid * 68 + tid];
    for (int off = 32; off; off >>= 1) v += __shfl_down(v, off);
    if (tid == 0) snorm = v;
  }
  __syncthreads();
  const float normA = snorm;
  const float inv = 1.f / normA;
  for (int e = tid; e < 4096; e += 256) {
    int i = e >> 6, j = e & 63;
    float an = bufs[0][i * 68 + j] * inv;
    bufs[0][i * 68 + j] = an;
    bufs[1][i * 68 + j] = 0.5f * ((i == j ? 3.f : 0.f) - an);
  }
  __syncthreads();
  mm64(bufs[2], bufs[0], bufs[1], tid, false);   // Y = An @ ZY0
  __syncthreads();
  float *Y = bufs[2], *Z = bufs[1], *Yn = bufs[4], *Zn = bufs[5];
  for (int it = 0; it < 3; ++it) {
    mm64(bufs[3], Z, Y, tid, true);              // ZY = 0.5*(3I - Z@Y)
    __syncthreads();
    mm64(Yn, Y, bufs[3], tid, false);            // Y' = Y @ ZY
    mm64(Zn, bufs[3], Z, tid, false);            // Z' = ZY @ Z
    __syncthreads();
    float* t0 = Y; Y = Yn; Yn = t0;
    float* t1 = Z; Z = Zn; Zn = t1;
  }
  mm64(bufs[3], Z, Y, tid, true);
  __syncthreads();
  mm64(Yn, Y, bufs[3], tid, false);              // YZY
  __syncthreads();
  if (tid < 64) {
    float s = 0.f;
    for (int i = 0; i < 64; ++i) s += Yn[i * 68 + tid];
    sS[tid] = s * (1.f / 64.f) * sqrtf(normA);
  }
  __syncthreads();
  if (tid < 8) {
    float h = b1[tid];
    for (int c2 = 0; c2 < 64; ++c2) h += w1[tid * 64 + c2] * sS[c2];
    sh[tid] = fmaxf(h, 0.f);
  }
  __syncthreads();
  if (tid < 64) {
    float l = b2[tid];
    for (int o = 0; o < 8; ++o) l += w2[tid * 8 + o] * sh[o];
    yout[b * 64 + tid] = 1.f / (1.f + expf(-l));
  }
}

// ---------------- Kernel 3: out = y[b,c] * (x - prev)
__global__ __launch_bounds__(256) void scale_k(const float* __restrict__ x,
                                               const float* __restrict__ prev,
                                               const float* __restrict__ y,
                                               float* __restrict__ out) {
  size_t f = (size_t)blockIdx.x * 256 + threadIdx.x;   // float4 index, total 8388608
  size_t e = f * 4;
  int bc = (int)(e >> 14);                              // (b*64 + c)
  float s = y[bc];
  float4 a = ((const float4*)x)[f];
  float4 p = ((const float4*)prev)[f];
  float4 o;
  o.x = (a.x - p.x) * s; o.y = (a.y - p.y) * s;
  o.z = (a.z - p.z) * s; o.w = (a.w - p.w) * s;
  ((float4*)out)[f] = o;
}

extern "C" void kernel_launch(void* const* d_in, const int* in_sizes, int n_in,
                              void* d_out, int out_size, void* d_ws, size_t ws_size,
                              hipStream_t stream) {
  (void)in_sizes; (void)n_in; (void)out_size; (void)ws_size;
  const float* prev = (const float*)d_in[0];
  const float* x    = (const float*)d_in[1];
  const float* w1   = (const float*)d_in[2];
  const float* b1   = (const float*)d_in[3];
  const float* w2   = (const float*)d_in[4];
  const float* b2   = (const float*)d_in[5];
  float* out = (float*)d_out;

  float* Gpart  = (float*)d_ws;                      // 1024*4096 f32 = 16 MB
  float* MuPart = Gpart + (size_t)1024 * 4096;       // 1024*64 f32
  float* yv     = MuPart + (size_t)1024 * 64;        // 32*64 f32

  gram_k<<<1024, 512, 0, stream>>>(x, prev, Gpart, MuPart);
  ns_k<<<32, 256, 0, stream>>>(Gpart, MuPart, w1, b1, w2, b2, yv);
  scale_k<<<32768, 256, 0, stream>>>(x, prev, yv, out);
}